// Round 4
// baseline (101.645 us; speedup 1.0000x reference)
//
#include <hip/hip_runtime.h>
#include <math.h>

// MultiPool: gather + CSR-segmented sum/mean/min/max, concat on dim 1.
// Inputs: embs [N=500000, D=128] f32, batches [T=1048576] i32, lens [B+1=65537] i32.
// Output: [B=65536, 4*D=512] f32  (sum | mean | min | max).
//
// Round 3 -> 4: remove the __shfl (ds_bpermute) from the gather-address
// critical path. Each lane now loads its segment's 16 indices directly as
// 4x int4 (same addresses across the 32-lane group -> L1 broadcast), so all
// 16 float4 gathers issue back-to-back with no DS dependency. Addresses are
// 32-bit offsets from the embs base (row*512B + col*4B < 2^28).

#ifndef INFINITY
#define INFINITY __builtin_huge_valf()
#endif

typedef float f32x4 __attribute__((ext_vector_type(4)));

constexpr int D = 128;
constexpr int LANES_PER_SEG = 32;   // D/4 columns per lane group
constexpr int SEGLEN = 16;

__global__ __launch_bounds__(256) void multipool_kernel(
    const float* __restrict__ embs,
    const int*   __restrict__ batches,
    const int*   __restrict__ lens,
    float*       __restrict__ out,
    int B)
{
    const int tid   = blockIdx.x * blockDim.x + threadIdx.x;
    const int seg   = tid >> 5;        // /32
    const int lane  = tid & 31;        // lane within segment group
    if (seg >= B) return;

    const int start = lens[seg];
    const int end   = lens[seg + 1];
    const int cnt   = end - start;

    const int col = lane * 4;

    f32x4 s  = {0.f, 0.f, 0.f, 0.f};
    f32x4 mn = { INFINITY,  INFINITY,  INFINITY,  INFINITY};
    f32x4 mx = {-INFINITY, -INFINITY, -INFINITY, -INFINITY};

    if (cnt == SEGLEN) {
        // Fast path (uniform segments). Load all 16 indices per-lane (L1
        // broadcast across the group), then issue 16 independent gathers.
        const int4* ip = reinterpret_cast<const int4*>(batches + start);
        const int4 i0 = ip[0], i1 = ip[1], i2 = ip[2], i3 = ip[3];
        const int rows[SEGLEN] = {i0.x, i0.y, i0.z, i0.w,
                                  i1.x, i1.y, i1.z, i1.w,
                                  i2.x, i2.y, i2.z, i2.w,
                                  i3.x, i3.y, i3.z, i3.w};

        f32x4 v[SEGLEN];
#pragma unroll
        for (int i = 0; i < SEGLEN; ++i) {
            const unsigned off = ((unsigned)rows[i] << 7) | (unsigned)col;
            v[i] = *reinterpret_cast<const f32x4*>(embs + off);
        }
#pragma unroll
        for (int i = 0; i < SEGLEN; ++i) {
            s += v[i];
            mn.x = fminf(mn.x, v[i].x); mn.y = fminf(mn.y, v[i].y);
            mn.z = fminf(mn.z, v[i].z); mn.w = fminf(mn.w, v[i].w);
            mx.x = fmaxf(mx.x, v[i].x); mx.y = fmaxf(mx.y, v[i].y);
            mx.z = fmaxf(mx.z, v[i].z); mx.w = fmaxf(mx.w, v[i].w);
        }
    } else {
        // Generic fallback (not hit for the benchmarked inputs).
        for (int i = start; i < end; ++i) {
            const int row = batches[i];
            const f32x4 v = *reinterpret_cast<const f32x4*>(
                embs + (size_t)row * D + col);
            s += v;
            mn.x = fminf(mn.x, v.x); mn.y = fminf(mn.y, v.y);
            mn.z = fminf(mn.z, v.z); mn.w = fminf(mn.w, v.w);
            mx.x = fmaxf(mx.x, v.x); mx.y = fmaxf(mx.y, v.y);
            mx.z = fmaxf(mx.z, v.z); mx.w = fmaxf(mx.w, v.w);
        }
    }

    const float inv = 1.0f / fmaxf((float)cnt, 1.0f);
    const f32x4 mean = s * inv;

    float* ob = out + (size_t)seg * (4 * D);
    __builtin_nontemporal_store(s,    reinterpret_cast<f32x4*>(ob + col));
    __builtin_nontemporal_store(mean, reinterpret_cast<f32x4*>(ob + D + col));
    __builtin_nontemporal_store(mn,   reinterpret_cast<f32x4*>(ob + 2 * D + col));
    __builtin_nontemporal_store(mx,   reinterpret_cast<f32x4*>(ob + 3 * D + col));
}

extern "C" void kernel_launch(void* const* d_in, const int* in_sizes, int n_in,
                              void* d_out, int out_size, void* d_ws, size_t ws_size,
                              hipStream_t stream) {
    const float* embs    = (const float*)d_in[0];
    const int*   batches = (const int*)d_in[1];
    const int*   lens    = (const int*)d_in[2];
    float*       out     = (float*)d_out;

    const int B = in_sizes[2] - 1;   // lens has B+1 entries

    const int threads = 256;
    const long long total_threads = (long long)B * LANES_PER_SEG;
    const int blocks = (int)((total_threads + threads - 1) / threads);

    multipool_kernel<<<blocks, threads, 0, stream>>>(embs, batches, lens, out, B);
}

// Round 5
// 95.274 us; speedup vs baseline: 1.0669x; 1.0669x over previous
//
#include <hip/hip_runtime.h>
#include <math.h>

// MultiPool: gather + CSR-segmented sum/mean/min/max, concat on dim 1.
// Inputs: embs [N=500000, D=128] f32, batches [T=1048576] i32, lens [B+1=65537] i32.
// Output: [B=65536, 4*D=512] f32  (sum | mean | min | max).
//
// Round 4 -> 5: one segment per 64-lane WAVE (lane owns 2 cols, f32x2).
// All control data (lens, batches rows) is wave-uniform; rows are moved to
// SGPRs via readfirstlane so each gather is saddr-form global_load_dwordx2
// with voffset = lane*8 — zero per-lane address VALU, ~60 VGPR total ->
// near-100% occupancy, 16 row-loads in flight per wave.

#ifndef INFINITY
#define INFINITY __builtin_huge_valf()
#endif

typedef float f32x2 __attribute__((ext_vector_type(2)));

constexpr int D = 128;
constexpr int SEGLEN = 16;

__global__ __launch_bounds__(256) void multipool_kernel(
    const float* __restrict__ embs,
    const int*   __restrict__ batches,
    const int*   __restrict__ lens,
    float*       __restrict__ out,
    int B)
{
    const int tid  = blockIdx.x * blockDim.x + threadIdx.x;
    const int seg  = tid >> 6;              // one segment per wave
    const int lane = threadIdx.x & 63;
    if (seg >= B) return;

    const int start = __builtin_amdgcn_readfirstlane(lens[seg]);
    const int end   = __builtin_amdgcn_readfirstlane(lens[seg + 1]);
    const int cnt   = end - start;

    const int col2 = lane * 2;              // this lane's 2 columns

    f32x2 s  = {0.f, 0.f};
    f32x2 mn = { INFINITY,  INFINITY};
    f32x2 mx = {-INFINITY, -INFINITY};

    if (cnt == SEGLEN) {
        // Wave-uniform index fetch (all lanes same addresses -> broadcast).
        const int4* ip = reinterpret_cast<const int4*>(batches + start);
        const int4 i0 = ip[0], i1 = ip[1], i2 = ip[2], i3 = ip[3];
        const int rows[SEGLEN] = {i0.x, i0.y, i0.z, i0.w,
                                  i1.x, i1.y, i1.z, i1.w,
                                  i2.x, i2.y, i2.z, i2.w,
                                  i3.x, i3.y, i3.z, i3.w};

        f32x2 v[SEGLEN];
#pragma unroll
        for (int i = 0; i < SEGLEN; ++i) {
            // SGPR row -> scalar base; voffset = lane*8.
            const int srow = __builtin_amdgcn_readfirstlane(rows[i]);
            const float* rowp = embs + ((size_t)(unsigned)srow << 7);
            v[i] = *reinterpret_cast<const f32x2*>(rowp + col2);
        }
#pragma unroll
        for (int i = 0; i < SEGLEN; ++i) {
            s += v[i];
            mn.x = fminf(mn.x, v[i].x); mn.y = fminf(mn.y, v[i].y);
            mx.x = fmaxf(mx.x, v[i].x); mx.y = fmaxf(mx.y, v[i].y);
        }
    } else {
        // Generic fallback (not hit for the benchmarked inputs).
        for (int i = start; i < end; ++i) {
            const int row = batches[i];
            const f32x2 v = *reinterpret_cast<const f32x2*>(
                embs + (size_t)(unsigned)row * D + col2);
            s += v;
            mn.x = fminf(mn.x, v.x); mn.y = fminf(mn.y, v.y);
            mx.x = fmaxf(mx.x, v.x); mx.y = fmaxf(mx.y, v.y);
        }
    }

    const float inv = 1.0f / fmaxf((float)cnt, 1.0f);
    const f32x2 mean = s * inv;

    float* ob = out + (size_t)seg * (4 * D);
    __builtin_nontemporal_store(s,    reinterpret_cast<f32x2*>(ob + col2));
    __builtin_nontemporal_store(mean, reinterpret_cast<f32x2*>(ob + D + col2));
    __builtin_nontemporal_store(mn,   reinterpret_cast<f32x2*>(ob + 2 * D + col2));
    __builtin_nontemporal_store(mx,   reinterpret_cast<f32x2*>(ob + 3 * D + col2));
}

extern "C" void kernel_launch(void* const* d_in, const int* in_sizes, int n_in,
                              void* d_out, int out_size, void* d_ws, size_t ws_size,
                              hipStream_t stream) {
    const float* embs    = (const float*)d_in[0];
    const int*   batches = (const int*)d_in[1];
    const int*   lens    = (const int*)d_in[2];
    float*       out     = (float*)d_out;

    const int B = in_sizes[2] - 1;   // lens has B+1 entries

    const int threads = 256;
    const long long total_threads = (long long)B * 64;   // one wave per segment
    const int blocks = (int)((total_threads + threads - 1) / threads);

    multipool_kernel<<<blocks, threads, 0, stream>>>(embs, batches, lens, out, B);
}